// Round 2
// baseline (244.233 us; speedup 1.0000x reference)
//
#include <hip/hip_runtime.h>
#include <cmath>

#define HW 3136          // 56*56
#define NF 64            // BB*LL frames
#define NBLK2 448        // NF * 7 row-tiles (conv blocks)

typedef __attribute__((ext_vector_type(8))) short short8;
typedef __attribute__((ext_vector_type(4))) float float4a;

__device__ __forceinline__ unsigned short f2bf(float f) {
    unsigned int u = __float_as_uint(f);
    u += 0x7fffu + ((u >> 16) & 1u);   // RNE
    return (unsigned short)(u >> 16);
}
__device__ __forceinline__ float bf2f(unsigned short u) {
    return __uint_as_float(((unsigned int)u) << 16);
}

// ---------------------------------------------------------------------------
// Kernel 0: pack DFT matrix (blocks 0..63) + repack conv_w (blocks 64..207).
// Ffix[p][t][ks][lane][j]: Astack_p[t*16+(lane&15)][ks*32+(lane>>4)*8+j]
//   Astack_0 = [Fr | -Fi] (K=112 pad 128), Astack_1 = [Fi | Fr]
// F symmetric => same array serves as A-frags (stage1) and B-frags (stage2).
// Wp[kk][o][i] bf16 from conv_w[o][i][kk] fp32.
// ---------------------------------------------------------------------------
__global__ __launch_bounds__(256)
void pack_kernel(const float* __restrict__ cw,
                 unsigned short* __restrict__ Ffix,
                 unsigned short* __restrict__ Wp) {
    if (blockIdx.x < 64) {
        int idx = blockIdx.x * 256 + threadIdx.x;    // 16384
        int j    = idx & 7;
        int lane = (idx >> 3) & 63;
        int ks   = (idx >> 9) & 3;
        int t    = (idx >> 11) & 3;
        int p    = (idx >> 13) & 1;
        int mn = t * 16 + (lane & 15);
        int k  = ks * 32 + (lane >> 4) * 8 + j;
        float val = 0.f;
        if (mn < 56 && k < 112) {
            int kk = (k < 56) ? k : k - 56;
            int prod = (mn * kk) % 56;
            float ang = -6.2831853071795864f * (float)prod / 56.0f;
            float cr = cosf(ang);
            float ci = sinf(ang);
            float first  = (p == 0) ? cr : ci;
            float second = (p == 0) ? -ci : cr;
            val = (k < 56) ? first : second;
        }
        Ffix[idx] = f2bf(val);
    } else {
        int idx = (blockIdx.x - 64) * 256 + threadIdx.x;
        if (idx < 36864) {
            int i  = idx & 63;
            int o  = (idx >> 6) & 63;
            int kk = idx >> 12;
            Wp[idx] = f2bf(cw[(o * 64 + i) * 9 + kk]);
        }
    }
}

// ---------------------------------------------------------------------------
// Kernel 1: FFT-pool via MFMA. One block per (b,c); x[b,:,c,:,:] staged to
// LDS as bf16 ONCE; loop lp=0..4 (conjugate symmetry gives lp=5..7 via flip).
// 512 threads / 8 waves; NO __launch_bounds__ min-waves clamp (round-1's
// (512,4) forced VGPR=64 -> 17 MB of scratch spills; bounded downside now).
//  Phase A: temporal DFT at lp from LDS -> Tb bf16 [w][k]
//  Phase B: U = F*T   wave wv: p=wv>>2, m-tile=wv&3
//  Phase C: G = U*F   wave wv: kh-tile=wv&3, kw-half=wv>>2, BOTH re/im parts
//           in-register (g[2][2]) -> magnitude without any LDS G buffer.
//  Epilogue: per-wave |G|-weighted sums vs x[lp] (+ flip vs x[8-lp])
// X-plane sums are lp-independent -> hoisted to one-time xsum[8] pass.
// LDS: 50176 + 30464 + 96 = 80736 B -> 2 blk/CU (LDS-limited) if VGPR<=128.
// ---------------------------------------------------------------------------
__global__ __launch_bounds__(512)
void fft_mfma_kernel(const float* __restrict__ x,
                     const unsigned short* __restrict__ Ffix,
                     float* __restrict__ pooled) {
    const int bc = blockIdx.x;           // 512 = b*64 + c
    const int c  = bc & 63;
    const int b  = bc >> 6;
    const int tid  = threadIdx.x;
    const int lane = tid & 63;
    const int wv   = tid >> 6;           // 0..7
    const int n    = lane & 15;
    const int q    = lane >> 4;

    __shared__ unsigned short sh[40320];
    unsigned short* xbf = sh;                         // [8][3136] bf16
    unsigned short* Tb  = sh + 25088;                 // rows 0..55, stride 136
    unsigned short* Ub  = sh + 25088 + 56 * 136;      // rows 0..55, stride 136
    __shared__ float xsum[8];
    __shared__ float red[16];

    // zero T/U region once (pad k-slots 112..135 must stay zero for MFMA)
    for (int t = tid; t < 7616; t += 512)
        ((unsigned int*)(sh + 25088))[t] = 0u;

    // stage x[b,:,c,:,:] -> bf16 LDS (one pass over x for whole kernel)
    for (int t = tid; t < 6272; t += 512) {           // 8l x 784 float4
        int l = t / 784, r = t - l * 784;
        float4 v = *(const float4*)(x + ((size_t)((b * 8 + l) * 64 + c)) * HW + r * 4);
        ushort4 o;
        o.x = f2bf(v.x); o.y = f2bf(v.y); o.z = f2bf(v.z); o.w = f2bf(v.w);
        *(ushort4*)(xbf + l * 3136 + r * 4) = o;
    }
    __syncthreads();

    // one-time per-plane sums (the X terms are lp-independent); wave wv owns
    // plane wv. Consumed only by tid 0 after several barriers.
    {
        float s = 0.f;
        for (int i = lane; i < 3136; i += 64) s += bf2f(xbf[wv * 3136 + i]);
        #pragma unroll
        for (int m = 1; m < 64; m <<= 1) s += __shfl_xor(s, m);
        if (lane == 0) xsum[wv] = s;
    }

    #pragma unroll 1
    for (int lp = 0; lp < 5; ++lp) {
        // ---- Phase A: temporal DFT at freq lp from LDS ----
        float tr[8], ti[8];
        #pragma unroll
        for (int l = 0; l < 8; ++l) {
            float ang = -0.78539816339744831f * (float)((l * lp) & 7);
            tr[l] = cosf(ang);
            ti[l] = sinf(ang);
        }
        for (int s = tid; s < 784; s += 512) {        // (h, w4)
            int h = s / 14, w4 = s - h * 14;
            float re[4] = {0.f, 0.f, 0.f, 0.f}, im[4] = {0.f, 0.f, 0.f, 0.f};
            #pragma unroll
            for (int l = 0; l < 8; ++l) {
                ushort4 u = *(const ushort4*)(xbf + l * 3136 + h * 56 + w4 * 4);
                float v0 = bf2f(u.x), v1 = bf2f(u.y), v2 = bf2f(u.z), v3 = bf2f(u.w);
                re[0] += v0 * tr[l]; im[0] += v0 * ti[l];
                re[1] += v1 * tr[l]; im[1] += v1 * ti[l];
                re[2] += v2 * tr[l]; im[2] += v2 * ti[l];
                re[3] += v3 * tr[l]; im[3] += v3 * ti[l];
            }
            #pragma unroll
            for (int j = 0; j < 4; ++j) {
                int w = w4 * 4 + j;
                Tb[w * 136 + h]      = f2bf(re[j]);
                Tb[w * 136 + 56 + h] = f2bf(im[j]);
            }
        }
        __syncthreads();

        // ---- Phase B: U = F * T.  wave wv: p = wv>>2, m-tile mt = wv&3 ----
        {
            const int p  = wv >> 2;          // 0: U_r, 1: U_i
            const int mt = wv & 3;
            float4a s1[4];
            #pragma unroll
            for (int nt = 0; nt < 4; ++nt) s1[nt] = (float4a){0.f, 0.f, 0.f, 0.f};
            #pragma unroll
            for (int ks = 0; ks < 4; ++ks) {
                short8 afr = *(const short8*)(Ffix + ((((p * 4 + mt) * 4 + ks) * 64 + lane) * 8));
                #pragma unroll
                for (int nt = 0; nt < 4; ++nt) {
                    int row = nt * 16 + n; if (row > 55) row = 55;  // clamp: cols discarded
                    short8 bfr = *(const short8*)(Tb + row * 136 + ks * 32 + q * 8);
                    s1[nt] = __builtin_amdgcn_mfma_f32_16x16x32_bf16(afr, bfr, s1[nt], 0, 0, 0);
                }
            }
            #pragma unroll
            for (int nt = 0; nt < 4; ++nt)
                #pragma unroll
                for (int r = 0; r < 4; ++r) {
                    int kh = mt * 16 + q * 4 + r;
                    int w  = nt * 16 + n;
                    if (kh < 56 && w < 56)
                        Ub[kh * 136 + p * 56 + w] = f2bf(s1[nt][r]);
                }
        }
        __syncthreads();

        // ---- Phase C: G = U * F.  wave wv: kh-tile mt = wv&3, kw-half nh ----
        const int mt = wv & 3;
        const int nh = wv >> 2;              // kw tiles nh*2, nh*2+1
        short8 afr2[4];
        #pragma unroll
        for (int ks = 0; ks < 4; ++ks) {
            int row = mt * 16 + n; if (row > 55) row = 55;          // clamp: rows discarded
            afr2[ks] = *(const short8*)(Ub + row * 136 + ks * 32 + q * 8);
        }
        float4a g[2][2];
        #pragma unroll
        for (int pp = 0; pp < 2; ++pp)
            #pragma unroll
            for (int u = 0; u < 2; ++u) g[pp][u] = (float4a){0.f, 0.f, 0.f, 0.f};
        #pragma unroll
        for (int pp = 0; pp < 2; ++pp)
            #pragma unroll
            for (int ks = 0; ks < 4; ++ks)
                #pragma unroll
                for (int u = 0; u < 2; ++u) {
                    int nt = nh * 2 + u;
                    short8 bfr = *(const short8*)(Ffix + ((((pp * 4 + nt) * 4 + ks) * 64 + lane) * 8));
                    g[pp][u] = __builtin_amdgcn_mfma_f32_16x16x32_bf16(afr2[ks], bfr, g[pp][u], 0, 0, 0);
                }

        // ---- Epilogue: fused magnitude + weighted sums from LDS x ----
        const bool doflip = (lp >= 1 && lp <= 3);
        const unsigned short* x1 = xbf + lp * 3136;
        const unsigned short* x2 = xbf + ((8 - lp) & 7) * 3136;
        float S1 = 0.f, S2 = 0.f;
        #pragma unroll
        for (int u = 0; u < 2; ++u) {
            int kw = (nh * 2 + u) * 16 + n;
            if (kw < 56) {
                int kwf = kw ? 56 - kw : 0;
                #pragma unroll
                for (int r = 0; r < 4; ++r) {
                    int kh = mt * 16 + q * 4 + r;
                    if (kh < 56) {
                        float gr = g[0][u][r], gi = g[1][u][r];
                        float mag = sqrtf(gr * gr + gi * gi);
                        S1 += mag * bf2f(x1[kh * 56 + kw]);
                        if (doflip) {
                            int khf = kh ? 56 - kh : 0;
                            S2 += mag * bf2f(x2[khf * 56 + kwf]);
                        }
                    }
                }
            }
        }
        #pragma unroll
        for (int m = 1; m < 64; m <<= 1) {
            S1 += __shfl_xor(S1, m);
            S2 += __shfl_xor(S2, m);
        }
        if (lane == 0) { red[wv * 2] = S1; red[wv * 2 + 1] = S2; }
        __syncthreads();
        if (tid == 0) {
            float s1 = 0.f, s2 = 0.f;
            #pragma unroll
            for (int w = 0; w < 8; ++w) { s1 += red[w * 2]; s2 += red[w * 2 + 1]; }
            const float kS = 0.01f / (56.0f * 2.8284271247461903f);
            pooled[bc * 8 + lp] = (xsum[lp] + kS * s1) / 3136.0f;
            if (doflip)
                pooled[bc * 8 + (8 - lp)] = (xsum[8 - lp] + kS * s2) / 3136.0f;
        }
    }
}

// ---------------------------------------------------------------------------
// Kernel 2: calib + fc
// ---------------------------------------------------------------------------
__global__ __launch_bounds__(64)
void calib_kernel(const float* __restrict__ pooled,
                  const float* __restrict__ tw_, const float* __restrict__ tb,
                  const float* __restrict__ fcw, const float* __restrict__ fcb,
                  const float* __restrict__ convb,
                  float* __restrict__ scale, float* __restrict__ fbias) {
    const int nn = blockIdx.x;
    const int b = nn >> 3, l = nn & 7;
    const int o = threadIdx.x;
    const float* pr = pooled + b * 512 + l;
    float dot = 0.f;
    #pragma unroll 8
    for (int c0 = 0; c0 < 64; ++c0) dot += tw_[o * 64 + c0] * pr[c0 * 8];
    float fcp = fcw[o] * pr[o * 8];
    #pragma unroll
    for (int off = 32; off > 0; off >>= 1) fcp += __shfl_down(fcp, off);
    float fcout = __shfl(fcp, 0) + fcb[0];
    scale[nn * 64 + o] = 1.0f + tb[o] + dot;
    fbias[nn * 64 + o] = convb[o] * (fcout + 1.0f);
}

// ---------------------------------------------------------------------------
// Kernel 3: conv as bf16 MFMA GEMM. Residual recovered from LDS:
// xs holds bf16(x*scale[i]); residual = bf2f(xs)/scale[o] (saves 51 MB fetch).
// ---------------------------------------------------------------------------
__global__ __launch_bounds__(256, 2)
void conv_mfma_kernel(const float* __restrict__ x,
                      const unsigned short* __restrict__ Wp,
                      const float* __restrict__ scale, const float* __restrict__ fbias,
                      float* __restrict__ out,
                      float* __restrict__ psum, float* __restrict__ psum2) {
    const int rt = blockIdx.x;
    const int nn = blockIdx.y;
    const int tid  = threadIdx.x;
    const int lane = tid & 63;
    const int wv   = tid >> 6;
    const int r0   = rt * 8;

    __shared__ unsigned short xs[10 * 60 * 64];   // 76.8 KB
    __shared__ float fb[64], ssc[64], rsc[64], bn1[64], bn2[64];

    if (tid < 64) {
        fb[tid]  = fbias[nn * 64 + tid];
        float s  = scale[nn * 64 + tid];
        ssc[tid] = s;
        rsc[tid] = 1.0f / s;
        bn1[tid] = 0.f; bn2[tid] = 0.f;
    }
    __syncthreads();

    for (int t = tid; t < 10240; t += 256) {
        if (t < 8960) {
            int c4 = t % 14;
            int rr = (t / 14) % 10;
            int i  = t / 140;
            int gr = r0 - 1 + rr;
            float4 v = make_float4(0.f, 0.f, 0.f, 0.f);
            if (gr >= 0 && gr < 56)
                v = *(const float4*)(x + ((size_t)(nn * 64 + i) * HW + gr * 56 + c4 * 4));
            float s = ssc[i];
            int g = i >> 3, il = i & 7;
            float vv[4] = {v.x, v.y, v.z, v.w};
            #pragma unroll
            for (int j = 0; j < 4; ++j) {
                int lc = c4 * 4 + 1 + j;
                xs[(rr * 60 + lc) * 64 + (((g ^ (lc & 7)) << 3) | il)] = f2bf(vv[j] * s);
            }
        } else {
            int idx = t - 8960;
            int i   = idx / 20;
            int rem = idx - i * 20;
            int rr  = rem >> 1;
            int lc  = (rem & 1) * 57;
            int g = i >> 3, il = i & 7;
            xs[(rr * 60 + lc) * 64 + (((g ^ (lc & 7)) << 3) | il)] = 0;
        }
    }
    __syncthreads();

    const int pxo = lane & 15;
    const int q   = lane >> 4;

    float4a acc[7][4];
    #pragma unroll
    for (int j = 0; j < 7; ++j)
        #pragma unroll
        for (int ot = 0; ot < 4; ++ot) acc[j][ot] = (float4a){0.f, 0.f, 0.f, 0.f};

    int rp[7], cp[7];
    #pragma unroll
    for (int j = 0; j < 7; ++j) {
        int px = (wv * 7 + j) * 16 + pxo;
        rp[j] = px / 56;
        cp[j] = px - rp[j] * 56;
    }

    #pragma unroll 1
    for (int kk = 0; kk < 9; ++kk) {
        const int dr = kk / 3, dc = kk - dr * 3;
        short8 a[4][2];
        #pragma unroll
        for (int ot = 0; ot < 4; ++ot)
            #pragma unroll
            for (int ih = 0; ih < 2; ++ih)
                a[ot][ih] = *(const short8*)(Wp + ((kk * 64 + ot * 16 + pxo) * 64 + ih * 32 + q * 8));

        #pragma unroll
        for (int j = 0; j < 7; ++j) {
            int lc = cp[j] + dc;
            int base = ((rp[j] + dr) * 60 + lc) * 64;
            int sw = lc & 7;
            #pragma unroll
            for (int ih = 0; ih < 2; ++ih) {
                short8 bv = *(const short8*)&xs[base + (((q + ih * 4) ^ sw) << 3)];
                #pragma unroll
                for (int ot = 0; ot < 4; ++ot)
                    acc[j][ot] = __builtin_amdgcn_mfma_f32_16x16x32_bf16(a[ot][ih], bv, acc[j][ot], 0, 0, 0);
            }
        }
    }

    float bs[4][4], bs2[4][4];
    #pragma unroll
    for (int ot = 0; ot < 4; ++ot)
        #pragma unroll
        for (int r = 0; r < 4; ++r) { bs[ot][r] = 0.f; bs2[ot][r] = 0.f; }

    #pragma unroll
    for (int j = 0; j < 7; ++j) {
        int px  = (wv * 7 + j) * 16 + pxo;
        int gpx = r0 * 56 + px;
        int rr  = rp[j] + 1;
        int lc  = cp[j] + 1;
        int sw  = lc & 7;
        int rowbase = (rr * 60 + lc) * 64;
        #pragma unroll
        for (int ot = 0; ot < 4; ++ot) {
            int g  = ot * 2 + (q >> 1);
            ushort4 uu = *(const ushort4*)(xs + rowbase + (((g ^ sw) << 3) | ((q & 1) * 4)));
            float resid[4] = {bf2f(uu.x), bf2f(uu.y), bf2f(uu.z), bf2f(uu.w)};
            #pragma unroll
            for (int r = 0; r < 4; ++r) {
                int o = ot * 16 + q * 4 + r;
                size_t off = (size_t)(nn * 64 + o) * HW + gpx;
                float v = acc[j][ot][r] + resid[r] * rsc[o] + fb[o];
                out[off] = v;
                bs[ot][r]  += v;
                bs2[ot][r] += v * v;
            }
        }
    }
    #pragma unroll
    for (int ot = 0; ot < 4; ++ot)
        #pragma unroll
        for (int r = 0; r < 4; ++r) {
            #pragma unroll
            for (int m = 1; m < 16; m <<= 1) {
                bs[ot][r]  += __shfl_xor(bs[ot][r], m);
                bs2[ot][r] += __shfl_xor(bs2[ot][r], m);
            }
        }
    if (pxo == 0) {
        #pragma unroll
        for (int ot = 0; ot < 4; ++ot)
            #pragma unroll
            for (int r = 0; r < 4; ++r) {
                int o = ot * 16 + q * 4 + r;
                atomicAdd(&bn1[o], bs[ot][r]);
                atomicAdd(&bn2[o], bs2[ot][r]);
            }
    }
    __syncthreads();
    if (tid < 64) {
        int bl = nn * 7 + rt;
        psum[bl * 64 + tid]  = bn1[tid];
        psum2[bl * 64 + tid] = bn2[tid];
    }
}

// ---------------------------------------------------------------------------
// Kernel 4: reduce partials -> per-channel mean / invstd
// ---------------------------------------------------------------------------
__global__ __launch_bounds__(256)
void bnstat_kernel(const float* __restrict__ psum, const float* __restrict__ psum2,
                   float* __restrict__ bn) {
    const int o = blockIdx.x;
    const int tid = threadIdx.x;
    float s = 0.f, s2 = 0.f;
    for (int bl = tid; bl < NBLK2; bl += 256) {
        s  += psum[bl * 64 + o];
        s2 += psum2[bl * 64 + o];
    }
    __shared__ float r1[256], r2[256];
    r1[tid] = s; r2[tid] = s2;
    __syncthreads();
    for (int st = 128; st > 0; st >>= 1) {
        if (tid < st) { r1[tid] += r1[tid + st]; r2[tid] += r2[tid + st]; }
        __syncthreads();
    }
    if (tid == 0) {
        const float N = 64.0f * (float)HW;
        float mean = r1[0] / N;
        float var  = r2[0] / N - mean * mean;
        bn[o]      = mean;
        bn[64 + o] = rsqrtf(var + 1e-5f);
    }
}

// ---------------------------------------------------------------------------
// Kernel 5: BN + SiLU in place
// ---------------------------------------------------------------------------
__global__ __launch_bounds__(256)
void bnsilu_kernel(float* __restrict__ out, const float* __restrict__ bn,
                   const float* __restrict__ gamma, const float* __restrict__ beta) {
    size_t idx = (size_t)blockIdx.x * 256 + threadIdx.x;
    if (idx >= (size_t)NF * 64 * HW) return;
    int c = (int)((idx / HW) & 63);
    float v = out[idx];
    float y = (v - bn[c]) * bn[64 + c] * gamma[c] + beta[c];
    out[idx] = y / (1.0f + expf(-y));
}

extern "C" void kernel_launch(void* const* d_in, const int* in_sizes, int n_in,
                              void* d_out, int out_size, void* d_ws, size_t ws_size,
                              hipStream_t stream) {
    const float* x          = (const float*)d_in[0];
    const float* temporal_w = (const float*)d_in[1];
    const float* temporal_b = (const float*)d_in[2];
    const float* fc_w       = (const float*)d_in[3];
    const float* fc_b       = (const float*)d_in[4];
    const float* conv_w     = (const float*)d_in[5];
    const float* conv_b     = (const float*)d_in[6];
    const float* bn_gamma   = (const float*)d_in[7];
    const float* bn_beta    = (const float*)d_in[8];
    float* out = (float*)d_out;
    float* ws  = (float*)d_ws;

    float* pooled = ws;                               // 4096 f
    float* scale  = ws + 4096;                        // 4096 f
    float* fbias  = ws + 8192;                        // 4096 f
    unsigned short* Wp = (unsigned short*)(ws + 12288);   // 36864 us = 18432 f
    float* psum   = ws + 12288 + 18432;               // 448*64 f
    float* psum2  = psum + NBLK2 * 64;                // 448*64 f
    float* bn     = psum2 + NBLK2 * 64;               // 128 f
    unsigned short* Ffix = (unsigned short*)(bn + 128);   // 16384 us

    pack_kernel<<<208, 256, 0, stream>>>(conv_w, Ffix, Wp);
    fft_mfma_kernel<<<512, 512, 0, stream>>>(x, Ffix, pooled);
    calib_kernel<<<64, 64, 0, stream>>>(pooled, temporal_w, temporal_b,
                                        fc_w, fc_b, conv_b, scale, fbias);
    conv_mfma_kernel<<<dim3(7, 64), 256, 0, stream>>>(x, Wp, scale, fbias,
                                                      out, psum, psum2);
    bnstat_kernel<<<64, 256, 0, stream>>>(psum, psum2, bn);
    int total = NF * 64 * HW;
    bnsilu_kernel<<<(total + 255) / 256, 256, 0, stream>>>(out, bn, bn_gamma, bn_beta);
}

// Round 3
// 232.223 us; speedup vs baseline: 1.0517x; 1.0517x over previous
//
#include <hip/hip_runtime.h>
#include <cmath>

#define HW 3136          // 56*56
#define NF 64            // BB*LL frames
#define NBLK2 448        // NF * 7 row-tiles (conv blocks)

typedef __attribute__((ext_vector_type(8))) short short8;
typedef __attribute__((ext_vector_type(4))) float float4a;

__device__ __forceinline__ unsigned short f2bf(float f) {
    unsigned int u = __float_as_uint(f);
    u += 0x7fffu + ((u >> 16) & 1u);   // RNE
    return (unsigned short)(u >> 16);
}
__device__ __forceinline__ float bf2f(unsigned short u) {
    return __uint_as_float(((unsigned int)u) << 16);
}

// ---------------------------------------------------------------------------
// Kernel 0: pack DFT matrix (blocks 0..63) + repack conv_w (blocks 64..207).
// k-slots are PERMUTED (pi): slot 2h = Re-column h, slot 2h+1 = Im-column h.
// Since both GEMM stages contract over k and the same pi is baked into Ffix
// and into the T/U slot layout, results are invariant (F symmetric).
//   Ffix[p][t][ks][lane][j]: A_p[t*16+(lane&15)][slot = ks*32+(lane>>4)*8+j]
//   p=0: slot even -> cos, odd -> -sin ; p=1: even -> sin, odd -> cos
// Wp[kk][o][i] bf16 from conv_w[o][i][kk] fp32.
// ---------------------------------------------------------------------------
__global__ __launch_bounds__(256)
void pack_kernel(const float* __restrict__ cw,
                 unsigned short* __restrict__ Ffix,
                 unsigned short* __restrict__ Wp) {
    if (blockIdx.x < 64) {
        int idx = blockIdx.x * 256 + threadIdx.x;    // 16384
        int j    = idx & 7;
        int lane = (idx >> 3) & 63;
        int ks   = (idx >> 9) & 3;
        int t    = (idx >> 11) & 3;
        int p    = (idx >> 13) & 1;
        int mn = t * 16 + (lane & 15);
        int k  = ks * 32 + (lane >> 4) * 8 + j;      // permuted slot
        float val = 0.f;
        if (mn < 56 && k < 112) {
            int h = k >> 1;                          // spatial column
            int prod = (mn * h) % 56;
            float ang = -6.2831853071795864f * (float)prod / 56.0f;
            float cr = cosf(ang);
            float ci = sinf(ang);
            if (p == 0) val = (k & 1) ? -ci : cr;    // [Fr | -Fi] interleaved
            else        val = (k & 1) ?  cr : ci;    // [Fi |  Fr] interleaved
        }
        Ffix[idx] = f2bf(val);
    } else {
        int idx = (blockIdx.x - 64) * 256 + threadIdx.x;
        if (idx < 36864) {
            int i  = idx & 63;
            int o  = (idx >> 6) & 63;
            int kk = idx >> 12;
            Wp[idx] = f2bf(cw[(o * 64 + i) * 9 + kk]);
        }
    }
}

// ---------------------------------------------------------------------------
// Kernel 1: FFT-pool via MFMA (R0 structure: 256 thr / 4 waves, 2 blk/CU).
//  Phase A: temporal DFT -> Tb, re/im PACKED as one uint per (w,h) at dword
//           w*68+h, store order rotated by w4 -> ~3.5-way banks (was ~13).
//  Phase B: U = F*T; Ub stored interleaved at slot 2w+p -> 2-way banks (free).
//  Phase C: G = U*F in-register (g[2][4]); epilogue fused magnitude sums.
// X-plane sums are lp-independent -> hoisted one-time xsum[8] pass.
// LDS: 50176 + 30464 + 64 = 80704 B -> 2 blk/CU.
// ---------------------------------------------------------------------------
__global__ __launch_bounds__(256, 2)
void fft_mfma_kernel(const float* __restrict__ x,
                     const unsigned short* __restrict__ Ffix,
                     float* __restrict__ pooled) {
    const int bc = blockIdx.x;           // 512 = b*64 + c
    const int c  = bc & 63;
    const int b  = bc >> 6;
    const int tid  = threadIdx.x;
    const int lane = tid & 63;
    const int wv   = tid >> 6;           // 0..3
    const int n    = lane & 15;
    const int q    = lane >> 4;

    __shared__ unsigned short sh[40320];
    unsigned short* xbf = sh;                         // [8][3136] bf16
    unsigned short* Tb  = sh + 25088;                 // rows 0..55 (w), stride 136
    unsigned short* Ub  = sh + 25088 + 56 * 136;      // rows 0..55 (kh), stride 136
    __shared__ float xsum[8];
    __shared__ float red[8];

    // zero T/U region once (pad k-slots 112..135 must stay zero)
    for (int t = tid; t < 7616; t += 256)
        ((unsigned int*)(sh + 25088))[t] = 0u;

    // stage x[b,:,c,:,:] -> bf16 LDS (one pass over x for whole kernel)
    for (int t = tid; t < 6272; t += 256) {           // 8l x 784 float4
        int l = t / 784, r = t - l * 784;
        float4 v = *(const float4*)(x + ((size_t)((b * 8 + l) * 64 + c)) * HW + r * 4);
        ushort4 o;
        o.x = f2bf(v.x); o.y = f2bf(v.y); o.z = f2bf(v.z); o.w = f2bf(v.w);
        *(ushort4*)(xbf + l * 3136 + r * 4) = o;
    }
    __syncthreads();

    // one-time per-plane sums (lp-independent): wave wv sums planes wv, wv+4.
    // Consumed only by tid 0 after >=2 barriers -> visibility guaranteed.
    {
        float s0 = 0.f, s4 = 0.f;
        for (int i = lane; i < 3136; i += 64) {
            s0 += bf2f(xbf[wv * 3136 + i]);
            s4 += bf2f(xbf[(wv + 4) * 3136 + i]);
        }
        #pragma unroll
        for (int m = 1; m < 64; m <<= 1) {
            s0 += __shfl_xor(s0, m);
            s4 += __shfl_xor(s4, m);
        }
        if (lane == 0) { xsum[wv] = s0; xsum[wv + 4] = s4; }
    }

    #pragma unroll 1
    for (int lp = 0; lp < 5; ++lp) {
        // ---- Phase A: temporal DFT at freq lp from LDS ----
        float tr[8], ti[8];
        #pragma unroll
        for (int l = 0; l < 8; ++l) {
            float ang = -0.78539816339744831f * (float)((l * lp) & 7);
            tr[l] = cosf(ang);
            ti[l] = sinf(ang);
        }
        for (int s = tid; s < 784; s += 256) {        // (h, w4)
            int h = s / 14, w4 = s - h * 14;
            float re[4] = {0.f, 0.f, 0.f, 0.f}, im[4] = {0.f, 0.f, 0.f, 0.f};
            #pragma unroll
            for (int l = 0; l < 8; ++l) {
                ushort4 u = *(const ushort4*)(xbf + l * 3136 + h * 56 + w4 * 4);
                float v0 = bf2f(u.x), v1 = bf2f(u.y), v2 = bf2f(u.z), v3 = bf2f(u.w);
                re[0] += v0 * tr[l]; im[0] += v0 * ti[l];
                re[1] += v1 * tr[l]; im[1] += v1 * ti[l];
                re[2] += v2 * tr[l]; im[2] += v2 * ti[l];
                re[3] += v3 * tr[l]; im[3] += v3 * ti[l];
            }
            // packed store: dword slot w*68+h holds (Re | Im<<16) = slots 2h,2h+1
            // store order rotated by w4 to spread banks
            #pragma unroll
            for (int jj = 0; jj < 4; ++jj) {
                int j = (jj + w4) & 3;
                int w = w4 * 4 + j;
                unsigned int pk = (unsigned int)f2bf(re[j])
                                | ((unsigned int)f2bf(im[j]) << 16);
                ((unsigned int*)Tb)[w * 68 + h] = pk;
            }
        }
        __syncthreads();

        // ---- Phase B: U = F * T.  wave wv: p = wv>>1, m-tiles (wv&1)*2 +mi ----
        {
            const int p  = wv >> 1;          // 0: U_r, 1: U_i
            const int mh = (wv & 1) * 2;     // m-tiles mh, mh+1
            float4a s1[2][4];
            #pragma unroll
            for (int mi = 0; mi < 2; ++mi)
                #pragma unroll
                for (int nt = 0; nt < 4; ++nt) s1[mi][nt] = (float4a){0.f, 0.f, 0.f, 0.f};
            #pragma unroll
            for (int ks = 0; ks < 4; ++ks) {
                short8 bfr[4];
                #pragma unroll
                for (int nt = 0; nt < 4; ++nt) {
                    int row = nt * 16 + n; if (row > 55) row = 55;  // clamp: cols discarded
                    bfr[nt] = *(const short8*)(Tb + row * 136 + ks * 32 + q * 8);
                }
                #pragma unroll
                for (int mi = 0; mi < 2; ++mi) {
                    short8 afr = *(const short8*)(Ffix + ((((p * 4 + mh + mi) * 4 + ks) * 64 + lane) * 8));
                    #pragma unroll
                    for (int nt = 0; nt < 4; ++nt)
                        s1[mi][nt] = __builtin_amdgcn_mfma_f32_16x16x32_bf16(afr, bfr[nt], s1[mi][nt], 0, 0, 0);
                }
            }
            // interleaved slot 2w+p matches pi-permuted Ffix for stage 2
            #pragma unroll
            for (int mi = 0; mi < 2; ++mi)
                #pragma unroll
                for (int nt = 0; nt < 4; ++nt)
                    #pragma unroll
                    for (int r = 0; r < 4; ++r) {
                        int kh = (mh + mi) * 16 + q * 4 + r;
                        int w  = nt * 16 + n;
                        if (kh < 56 && w < 56)
                            Ub[kh * 136 + 2 * w + p] = f2bf(s1[mi][nt][r]);
                    }
        }
        __syncthreads();

        // ---- Phase C: G = U * F (wave wv owns kh-tile wv, both parts) ----
        const int mt = wv;
        short8 afr2[4];
        #pragma unroll
        for (int ks = 0; ks < 4; ++ks) {
            int row = mt * 16 + n; if (row > 55) row = 55;          // clamp: rows discarded
            afr2[ks] = *(const short8*)(Ub + row * 136 + ks * 32 + q * 8);
        }
        float4a g[2][4];
        #pragma unroll
        for (int pp = 0; pp < 2; ++pp)
            #pragma unroll
            for (int nt = 0; nt < 4; ++nt) g[pp][nt] = (float4a){0.f, 0.f, 0.f, 0.f};
        #pragma unroll
        for (int pp = 0; pp < 2; ++pp)
            #pragma unroll
            for (int ks = 0; ks < 4; ++ks)
                #pragma unroll
                for (int nt = 0; nt < 4; ++nt) {
                    short8 bfr = *(const short8*)(Ffix + ((((pp * 4 + nt) * 4 + ks) * 64 + lane) * 8));
                    g[pp][nt] = __builtin_amdgcn_mfma_f32_16x16x32_bf16(afr2[ks], bfr, g[pp][nt], 0, 0, 0);
                }

        // ---- Epilogue: fused magnitude + weighted sums from LDS x ----
        const bool doflip = (lp >= 1 && lp <= 3);
        const unsigned short* x1 = xbf + lp * 3136;
        const unsigned short* x2 = xbf + ((8 - lp) & 7) * 3136;
        float S1 = 0.f, S2 = 0.f;
        #pragma unroll
        for (int nt = 0; nt < 4; ++nt) {
            int kw = nt * 16 + n;
            if (kw < 56) {
                int kwf = (56 - kw) % 56;
                #pragma unroll
                for (int r = 0; r < 4; ++r) {
                    int kh = mt * 16 + q * 4 + r;
                    if (kh < 56) {
                        float gr = g[0][nt][r], gi = g[1][nt][r];
                        float mag = sqrtf(gr * gr + gi * gi);
                        S1 += mag * bf2f(x1[kh * 56 + kw]);
                        if (doflip) {
                            int khf = (56 - kh) % 56;
                            S2 += mag * bf2f(x2[khf * 56 + kwf]);
                        }
                    }
                }
            }
        }
        #pragma unroll
        for (int m = 1; m < 64; m <<= 1) {
            S1 += __shfl_xor(S1, m);
            S2 += __shfl_xor(S2, m);
        }
        if (lane == 0) { red[wv * 2] = S1; red[wv * 2 + 1] = S2; }
        __syncthreads();
        if (tid == 0) {
            float s1 = 0.f, s2 = 0.f;
            #pragma unroll
            for (int w = 0; w < 4; ++w) { s1 += red[w * 2]; s2 += red[w * 2 + 1]; }
            const float kS = 0.01f / (56.0f * 2.8284271247461903f);
            pooled[bc * 8 + lp] = (xsum[lp] + kS * s1) / 3136.0f;
            if (doflip)
                pooled[bc * 8 + (8 - lp)] = (xsum[8 - lp] + kS * s2) / 3136.0f;
        }
    }
}

// ---------------------------------------------------------------------------
// Kernel 2: calib + fc
// ---------------------------------------------------------------------------
__global__ __launch_bounds__(64)
void calib_kernel(const float* __restrict__ pooled,
                  const float* __restrict__ tw_, const float* __restrict__ tb,
                  const float* __restrict__ fcw, const float* __restrict__ fcb,
                  const float* __restrict__ convb,
                  float* __restrict__ scale, float* __restrict__ fbias) {
    const int nn = blockIdx.x;
    const int b = nn >> 3, l = nn & 7;
    const int o = threadIdx.x;
    const float* pr = pooled + b * 512 + l;
    float dot = 0.f;
    #pragma unroll 8
    for (int c0 = 0; c0 < 64; ++c0) dot += tw_[o * 64 + c0] * pr[c0 * 8];
    float fcp = fcw[o] * pr[o * 8];
    #pragma unroll
    for (int off = 32; off > 0; off >>= 1) fcp += __shfl_down(fcp, off);
    float fcout = __shfl(fcp, 0) + fcb[0];
    scale[nn * 64 + o] = 1.0f + tb[o] + dot;
    fbias[nn * 64 + o] = convb[o] * (fcout + 1.0f);
}

// ---------------------------------------------------------------------------
// Kernel 3: conv as bf16 MFMA GEMM. Residual recovered from LDS:
// xs holds bf16(x*scale[i]); residual = bf2f(xs)/scale[o] (saves 51 MB fetch).
// ---------------------------------------------------------------------------
__global__ __launch_bounds__(256, 2)
void conv_mfma_kernel(const float* __restrict__ x,
                      const unsigned short* __restrict__ Wp,
                      const float* __restrict__ scale, const float* __restrict__ fbias,
                      float* __restrict__ out,
                      float* __restrict__ psum, float* __restrict__ psum2) {
    const int rt = blockIdx.x;
    const int nn = blockIdx.y;
    const int tid  = threadIdx.x;
    const int lane = tid & 63;
    const int wv   = tid >> 6;
    const int r0   = rt * 8;

    __shared__ unsigned short xs[10 * 60 * 64];   // 76.8 KB
    __shared__ float fb[64], ssc[64], rsc[64], bn1[64], bn2[64];

    if (tid < 64) {
        fb[tid]  = fbias[nn * 64 + tid];
        float s  = scale[nn * 64 + tid];
        ssc[tid] = s;
        rsc[tid] = 1.0f / s;
        bn1[tid] = 0.f; bn2[tid] = 0.f;
    }
    __syncthreads();

    for (int t = tid; t < 10240; t += 256) {
        if (t < 8960) {
            int c4 = t % 14;
            int rr = (t / 14) % 10;
            int i  = t / 140;
            int gr = r0 - 1 + rr;
            float4 v = make_float4(0.f, 0.f, 0.f, 0.f);
            if (gr >= 0 && gr < 56)
                v = *(const float4*)(x + ((size_t)(nn * 64 + i) * HW + gr * 56 + c4 * 4));
            float s = ssc[i];
            int g = i >> 3, il = i & 7;
            float vv[4] = {v.x, v.y, v.z, v.w};
            #pragma unroll
            for (int j = 0; j < 4; ++j) {
                int lc = c4 * 4 + 1 + j;
                xs[(rr * 60 + lc) * 64 + (((g ^ (lc & 7)) << 3) | il)] = f2bf(vv[j] * s);
            }
        } else {
            int idx = t - 8960;
            int i   = idx / 20;
            int rem = idx - i * 20;
            int rr  = rem >> 1;
            int lc  = (rem & 1) * 57;
            int g = i >> 3, il = i & 7;
            xs[(rr * 60 + lc) * 64 + (((g ^ (lc & 7)) << 3) | il)] = 0;
        }
    }
    __syncthreads();

    const int pxo = lane & 15;
    const int q   = lane >> 4;

    float4a acc[7][4];
    #pragma unroll
    for (int j = 0; j < 7; ++j)
        #pragma unroll
        for (int ot = 0; ot < 4; ++ot) acc[j][ot] = (float4a){0.f, 0.f, 0.f, 0.f};

    int rp[7], cp[7];
    #pragma unroll
    for (int j = 0; j < 7; ++j) {
        int px = (wv * 7 + j) * 16 + pxo;
        rp[j] = px / 56;
        cp[j] = px - rp[j] * 56;
    }

    #pragma unroll 1
    for (int kk = 0; kk < 9; ++kk) {
        const int dr = kk / 3, dc = kk - dr * 3;
        short8 a[4][2];
        #pragma unroll
        for (int ot = 0; ot < 4; ++ot)
            #pragma unroll
            for (int ih = 0; ih < 2; ++ih)
                a[ot][ih] = *(const short8*)(Wp + ((kk * 64 + ot * 16 + pxo) * 64 + ih * 32 + q * 8));

        #pragma unroll
        for (int j = 0; j < 7; ++j) {
            int lc = cp[j] + dc;
            int base = ((rp[j] + dr) * 60 + lc) * 64;
            int sw = lc & 7;
            #pragma unroll
            for (int ih = 0; ih < 2; ++ih) {
                short8 bv = *(const short8*)&xs[base + (((q + ih * 4) ^ sw) << 3)];
                #pragma unroll
                for (int ot = 0; ot < 4; ++ot)
                    acc[j][ot] = __builtin_amdgcn_mfma_f32_16x16x32_bf16(a[ot][ih], bv, acc[j][ot], 0, 0, 0);
            }
        }
    }

    float bs[4][4], bs2[4][4];
    #pragma unroll
    for (int ot = 0; ot < 4; ++ot)
        #pragma unroll
        for (int r = 0; r < 4; ++r) { bs[ot][r] = 0.f; bs2[ot][r] = 0.f; }

    #pragma unroll
    for (int j = 0; j < 7; ++j) {
        int px  = (wv * 7 + j) * 16 + pxo;
        int gpx = r0 * 56 + px;
        int rr  = rp[j] + 1;
        int lc  = cp[j] + 1;
        int sw  = lc & 7;
        int rowbase = (rr * 60 + lc) * 64;
        #pragma unroll
        for (int ot = 0; ot < 4; ++ot) {
            int g  = ot * 2 + (q >> 1);
            ushort4 uu = *(const ushort4*)(xs + rowbase + (((g ^ sw) << 3) | ((q & 1) * 4)));
            float resid[4] = {bf2f(uu.x), bf2f(uu.y), bf2f(uu.z), bf2f(uu.w)};
            #pragma unroll
            for (int r = 0; r < 4; ++r) {
                int o = ot * 16 + q * 4 + r;
                size_t off = (size_t)(nn * 64 + o) * HW + gpx;
                float v = acc[j][ot][r] + resid[r] * rsc[o] + fb[o];
                out[off] = v;
                bs[ot][r]  += v;
                bs2[ot][r] += v * v;
            }
        }
    }
    #pragma unroll
    for (int ot = 0; ot < 4; ++ot)
        #pragma unroll
        for (int r = 0; r < 4; ++r) {
            #pragma unroll
            for (int m = 1; m < 16; m <<= 1) {
                bs[ot][r]  += __shfl_xor(bs[ot][r], m);
                bs2[ot][r] += __shfl_xor(bs2[ot][r], m);
            }
        }
    if (pxo == 0) {
        #pragma unroll
        for (int ot = 0; ot < 4; ++ot)
            #pragma unroll
            for (int r = 0; r < 4; ++r) {
                int o = ot * 16 + q * 4 + r;
                atomicAdd(&bn1[o], bs[ot][r]);
                atomicAdd(&bn2[o], bs2[ot][r]);
            }
    }
    __syncthreads();
    if (tid < 64) {
        int bl = nn * 7 + rt;
        psum[bl * 64 + tid]  = bn1[tid];
        psum2[bl * 64 + tid] = bn2[tid];
    }
}

// ---------------------------------------------------------------------------
// Kernel 4: reduce partials -> per-channel mean / invstd
// ---------------------------------------------------------------------------
__global__ __launch_bounds__(256)
void bnstat_kernel(const float* __restrict__ psum, const float* __restrict__ psum2,
                   float* __restrict__ bn) {
    const int o = blockIdx.x;
    const int tid = threadIdx.x;
    float s = 0.f, s2 = 0.f;
    for (int bl = tid; bl < NBLK2; bl += 256) {
        s  += psum[bl * 64 + o];
        s2 += psum2[bl * 64 + o];
    }
    __shared__ float r1[256], r2[256];
    r1[tid] = s; r2[tid] = s2;
    __syncthreads();
    for (int st = 128; st > 0; st >>= 1) {
        if (tid < st) { r1[tid] += r1[tid + st]; r2[tid] += r2[tid + st]; }
        __syncthreads();
    }
    if (tid == 0) {
        const float N = 64.0f * (float)HW;
        float mean = r1[0] / N;
        float var  = r2[0] / N - mean * mean;
        bn[o]      = mean;
        bn[64 + o] = rsqrtf(var + 1e-5f);
    }
}

// ---------------------------------------------------------------------------
// Kernel 5: BN + SiLU in place
// ---------------------------------------------------------------------------
__global__ __launch_bounds__(256)
void bnsilu_kernel(float* __restrict__ out, const float* __restrict__ bn,
                   const float* __restrict__ gamma, const float* __restrict__ beta) {
    size_t idx = (size_t)blockIdx.x * 256 + threadIdx.x;
    if (idx >= (size_t)NF * 64 * HW) return;
    int c = (int)((idx / HW) & 63);
    float v = out[idx];
    float y = (v - bn[c]) * bn[64 + c] * gamma[c] + beta[c];
    out[idx] = y / (1.0f + expf(-y));
}

extern "C" void kernel_launch(void* const* d_in, const int* in_sizes, int n_in,
                              void* d_out, int out_size, void* d_ws, size_t ws_size,
                              hipStream_t stream) {
    const float* x          = (const float*)d_in[0];
    const float* temporal_w = (const float*)d_in[1];
    const float* temporal_b = (const float*)d_in[2];
    const float* fc_w       = (const float*)d_in[3];
    const float* fc_b       = (const float*)d_in[4];
    const float* conv_w     = (const float*)d_in[5];
    const float* conv_b     = (const float*)d_in[6];
    const float* bn_gamma   = (const float*)d_in[7];
    const float* bn_beta    = (const float*)d_in[8];
    float* out = (float*)d_out;
    float* ws  = (float*)d_ws;

    float* pooled = ws;                               // 4096 f
    float* scale  = ws + 4096;                        // 4096 f
    float* fbias  = ws + 8192;                        // 4096 f
    unsigned short* Wp = (unsigned short*)(ws + 12288);   // 36864 us = 18432 f
    float* psum   = ws + 12288 + 18432;               // 448*64 f
    float* psum2  = psum + NBLK2 * 64;                // 448*64 f
    float* bn     = psum2 + NBLK2 * 64;               // 128 f
    unsigned short* Ffix = (unsigned short*)(bn + 128);   // 16384 us

    pack_kernel<<<208, 256, 0, stream>>>(conv_w, Ffix, Wp);
    fft_mfma_kernel<<<512, 256, 0, stream>>>(x, Ffix, pooled);
    calib_kernel<<<64, 64, 0, stream>>>(pooled, temporal_w, temporal_b,
                                        fc_w, fc_b, conv_b, scale, fbias);
    conv_mfma_kernel<<<dim3(7, 64), 256, 0, stream>>>(x, Wp, scale, fbias,
                                                      out, psum, psum2);
    bnstat_kernel<<<64, 256, 0, stream>>>(psum, psum2, bn);
    int total = NF * 64 * HW;
    bnsilu_kernel<<<(total + 255) / 256, 256, 0, stream>>>(out, bn, bn_gamma, bn_beta);
}